// Round 1
// baseline (163.832 us; speedup 1.0000x reference)
//
#include <hip/hip_runtime.h>
#include <cmath>

// ---------------------------------------------------------------------------
// NeuralField: hashgrid encode (8 levels x 8 feats, smoothstep) + MLP
// 64 -> 256 -> 256 -> 256 -> 1 (ReLU x3, linear out), N = 262144 points.
// R13: attack LDS datapath + L2 redundancy (R12 was 105 us @ 33% MfmaUtil;
// accounting: ~56 us LDS b128 traffic, ~43 us L2 weight/table re-fetch vs
// 31 us matrix floor). Waves now own 64 feats x 64 pts (4 MFMAs/k-step,
// acc 2x2 f32x16) and TILE_M=128:
//   - act B-frag re-reads per point per layer: 4 -> 2  (LDS ~56 -> ~31 us)
//   - weight L2 bytes: 1.18 GB -> 0.59 GB              (L2  ~43 -> ~26 us)
//   - MFMA work unchanged (31 us floor)
// Encode output lives in bufA cols 0..63 (L0 runs in-place, mid-layer
// barrier between last K-loop read and epilogue write -- mechanism proven
// R6). LDS 70 KB -> 2 blocks/CU (16 waves/CU). VGPR ~120, cap 128 via
// __launch_bounds__(512,4). Spill tripwire: VGPR=128 + FETCH/WRITE >> 6 MB.
// ---------------------------------------------------------------------------

#define N_LEVELS 8
#define TABLE_PAD 8192
#define TILE_M 128
#define ACT_STRIDE 264       // shorts per activation row (256 + 8 pad)

typedef __attribute__((ext_vector_type(8))) short short8;
typedef __attribute__((ext_vector_type(16))) float float16v;

struct LevelParams {
  float scale[N_LEVELS];
  int   res[N_LEVELS];
  int   size[N_LEVELS];
};

__device__ __forceinline__ unsigned short f2bf(float f) {
  unsigned int u = __float_as_uint(f);
  u += 0x7fffu + ((u >> 16) & 1u);      // round to nearest even
  return (unsigned short)(u >> 16);
}
__device__ __forceinline__ unsigned int pack2bf(float a, float b) {
  a = a > 0.f ? a : 0.f;
  b = b > 0.f ? b : 0.f;
  return (unsigned int)f2bf(a) | ((unsigned int)f2bf(b) << 16);
}

// Pack W (K x 256 row-major f32) -> bf16 [k/16][n][k%16]: one lane's 16 B
// A-frag for 32x32x16 (feature n, k-half h8) is contiguous at n*16 + h8*8.
// Wp layout: [W0p: 4*4096][W1p: 16*4096][W2p: 16*4096] shorts.
__global__ void pack_weights_kernel(const float* __restrict__ W0,
                                    const float* __restrict__ W1,
                                    const float* __restrict__ W2,
                                    unsigned short* __restrict__ Wp) {
  int tid = blockIdx.x * blockDim.x + threadIdx.x;
  const float* src;
  int base, e;
  if (tid < 16384)        { src = W0; base = 0;     e = tid;         }
  else if (tid < 81920)   { src = W1; base = 16384; e = tid - 16384; }
  else if (tid < 147456)  { src = W2; base = 81920; e = tid - 81920; }
  else return;
  int ki = e & 15;
  int n  = (e >> 4) & 255;
  int kb = e >> 12;
  unsigned int u = __float_as_uint(src[(kb * 16 + ki) * 256 + n]);
  u += 0x7fffu + ((u >> 16) & 1u);
  Wp[base + e] = (unsigned short)(u >> 16);
}

__global__ __launch_bounds__(512, 4) void neural_field_kernel(
    const float* __restrict__ x,
    const float* __restrict__ table,
    const unsigned short* __restrict__ Wp,
    const float* __restrict__ W3,
    float* __restrict__ out,
    LevelParams P) {
  // One activation buffer, data stored [point m][feature k], in-place for
  // every layer: enc lives in cols 0..63, each layer reads all it needs,
  // hits the inner barrier, then overwrites.
  __shared__ unsigned short bufA[TILE_M * ACT_STRIDE];   // 67584 B
  __shared__ float fsum[TILE_M * 5];                     //  2560 B

  const int t  = threadIdx.x;
  const int g0 = blockIdx.x * TILE_M;

  const int lane  = t & 63;
  const int w     = t >> 6;       // 0..7
  const int l31   = lane & 31;
  const int h8    = lane >> 5;    // 0/1: k-half within a 16-k step
  const int fg    = w & 3;        // feature group: 64 output feats
  const int pg    = w >> 2;       // point group: 64 points
  const int wbase = fg * 64;
  const int mbase = pg * 64;

  // Per-wave weight A-frag base offset (elements) in a layer's packed W.
  // Feat-tile 1 is at +512 (32 feats * 16 k-elems).
  const int woff = (wbase + l31) * 16 + h8 * 8;

  // ------------- Phase 1: hashgrid encode, 2 levels/thread -> bufA --------
  {
    int p  = t & 127;      // point within tile
    int lb = t >> 7;       // level base 0..3; this thread does lb and lb+4
    float2 xy = ((const float2*)x)[g0 + p];
#pragma unroll
    for (int li = 0; li < 2; ++li) {
      int l = lb + li * 4;
      float scale = P.scale[l];
      int res = P.res[l], size = P.size[l];
      float posx = xy.x * scale + 0.5f;
      float posy = xy.y * scale + 0.5f;
      float pgx = floorf(posx), pgy = floorf(posy);
      float fx = posx - pgx, fy = posy - pgy;
      float wxv = fx * fx * (3.0f - 2.0f * fx);
      float wyv = fy * fy * (3.0f - 2.0f * fy);
      int px = (int)pgx, py = (int)pgy;
      float acc[8] = {0, 0, 0, 0, 0, 0, 0, 0};
      for (int dy = 0; dy < 2; ++dy) {
        float wy2 = dy ? wyv : 1.0f - wyv;
        for (int dx = 0; dx < 2; ++dx) {
          float wgt = (dx ? wxv : 1.0f - wxv) * wy2;
          int idx = (px + dx) + (py + dy) * res;
          if (idx >= size) idx -= size;   // idx < 2*size always
          const float4* tp =
              (const float4*)(table + ((size_t)l * TABLE_PAD + idx) * 8);
          float4 t0 = tp[0], t1 = tp[1];
          acc[0] += wgt * t0.x; acc[1] += wgt * t0.y;
          acc[2] += wgt * t0.z; acc[3] += wgt * t0.w;
          acc[4] += wgt * t1.x; acc[5] += wgt * t1.y;
          acc[6] += wgt * t1.z; acc[7] += wgt * t1.w;
        }
      }
      union { unsigned short s[8]; short8 v; } u;
      for (int j = 0; j < 8; ++j) u.s[j] = f2bf(acc[j]);
      *(short8*)&bufA[p * ACT_STRIDE + l * 8] = u.v;
    }
  }

  // ---- MFMA layer (transposed, 32x32x16): D = W^T[64 x K] @ X^T[K x 64] --
  // Per wave: 2 feat-tiles (wbase+0/+32) x 2 pt-tiles (mbase+0/+32),
  // 4 MFMAs per 16-k step, acc[ft][pt] f32x16 (64 VGPR).
  // A-frag (weights): row n = base+l31, k = kb*16 + h8*8 + j  (from L2).
  // B-frag (acts):    col m = base+l31, k = kb*16 + h8*8 + j  (from LDS).
  // D: col m = tile+l31; reg 4q+r -> n = tile + 8q + 4h8 + r.
  // In-place: barrier between last K-loop read and the epilogue overwrite.
  auto run_layer = [&](const unsigned short* Wpl, int KB,
                       short8 wfa, short8 wfb, bool fuse_final) {
    float16v acc[2][2];
#pragma unroll
    for (int j = 0; j < 16; ++j) {
      acc[0][0][j] = 0.f; acc[0][1][j] = 0.f;
      acc[1][0][j] = 0.f; acc[1][1][j] = 0.f;
    }

    const unsigned short* ap0 = &bufA[(mbase + l31) * ACT_STRIDE + h8 * 8];
    const unsigned short* ap1 = ap0 + 32 * ACT_STRIDE;
    const unsigned short* wp  = Wpl + woff;

#pragma unroll
    for (int kb = 0; kb < KB; ++kb) {
      int kn = (kb + 1 < KB) ? kb + 1 : kb;
      short8 wna = *(const short8*)(wp + kn * 4096);
      short8 wnb = *(const short8*)(wp + kn * 4096 + 512);
      short8 bf0 = *(const short8*)(ap0 + kb * 16);
      short8 bf1 = *(const short8*)(ap1 + kb * 16);
      acc[0][0] = __builtin_amdgcn_mfma_f32_32x32x16_bf16(wfa, bf0,
                                                          acc[0][0], 0, 0, 0);
      acc[0][1] = __builtin_amdgcn_mfma_f32_32x32x16_bf16(wfa, bf1,
                                                          acc[0][1], 0, 0, 0);
      acc[1][0] = __builtin_amdgcn_mfma_f32_32x32x16_bf16(wfb, bf0,
                                                          acc[1][0], 0, 0, 0);
      acc[1][1] = __builtin_amdgcn_mfma_f32_32x32x16_bf16(wfb, bf1,
                                                          acc[1][1], 0, 0, 0);
      wfa = wna; wfb = wnb;
    }

    if (!fuse_final) {
      __syncthreads();   // all K-loop reads of bufA done before overwrite
      // Epilogue: ReLU + bf16 pack; writes land in next layer's
      // [m][k-contiguous] layout.
#pragma unroll
      for (int ft = 0; ft < 2; ++ft) {
#pragma unroll
        for (int pt = 0; pt < 2; ++pt) {
          int m  = mbase + pt * 32 + l31;
          int n0 = wbase + ft * 32 + 4 * h8;
#pragma unroll
          for (int q = 0; q < 4; ++q) {
            uint2 pk;
            pk.x = pack2bf(acc[ft][pt][4 * q + 0], acc[ft][pt][4 * q + 1]);
            pk.y = pack2bf(acc[ft][pt][4 * q + 2], acc[ft][pt][4 * q + 3]);
            *(uint2*)&bufA[m * ACT_STRIDE + n0 + 8 * q] = pk;
          }
        }
      }
    } else {
      // Fused final layer: per-lane relu-dot over this wave's 64 features
      // (w3f loaded AFTER the K-loop to keep it out of live range),
      // combine k-halves via shfl_xor(32), stage per-wave partials to
      // fsum[m*5 + fg].
      float part0 = 0.f, part1 = 0.f;
#pragma unroll
      for (int ft = 0; ft < 2; ++ft) {
#pragma unroll
        for (int q = 0; q < 4; ++q) {
          float4 wv = *(const float4*)(W3 + wbase + ft * 32 + 8 * q + 4 * h8);
          float w3v[4] = {wv.x, wv.y, wv.z, wv.w};
#pragma unroll
          for (int r = 0; r < 4; ++r) {
            float v0 = acc[ft][0][4 * q + r]; v0 = v0 > 0.f ? v0 : 0.f;
            float v1 = acc[ft][1][4 * q + r]; v1 = v1 > 0.f ? v1 : 0.f;
            part0 += v0 * w3v[r];
            part1 += v1 * w3v[r];
          }
        }
      }
      part0 += __shfl_xor(part0, 32);
      part1 += __shfl_xor(part1, 32);
      // pt0 cols = mbase+l31 (h8=0 lanes), pt1 cols = mbase+32+l31 (h8=1):
      // both equal mbase + lane.
      fsum[(mbase + lane) * 5 + fg] = h8 ? part1 : part0;
    }
  };

  short8 wfa = *(const short8*)(Wp + woff);            // L0 wf preload
  short8 wfb = *(const short8*)(Wp + woff + 512);
  __syncthreads();
  // Layer 0: reads cols 0..63 (K=64), overwrites cols 0..255 in-place
  run_layer(Wp, 4, wfa, wfb, false);
  wfa = *(const short8*)(Wp + 16384 + woff);           // L1 wf preload
  wfb = *(const short8*)(Wp + 16384 + woff + 512);
  __syncthreads();
  // Layer 1: bufA -> bufA in-place (mid-layer barrier inside)
  run_layer(Wp + 16384, 16, wfa, wfb, false);
  wfa = *(const short8*)(Wp + 81920 + woff);           // L2 wf preload
  wfb = *(const short8*)(Wp + 81920 + woff + 512);
  __syncthreads();
  // Layer 2 + final: reads bufA, writes only fsum (disjoint)
  run_layer(Wp + 81920, 16, wfa, wfb, true);
  __syncthreads();

  // ---------------- Cross-wave reduce of fsum -> out -----------------------
  {
    int p = t >> 2;          // point within tile (0..127)
    int q = t & 3;           // feature-group partial being summed
    float v = fsum[p * 5 + q];
    v += __shfl_xor(v, 1);
    v += __shfl_xor(v, 2);
    if (q == 0) out[g0 + p] = v;
  }
}

extern "C" void kernel_launch(void* const* d_in, const int* in_sizes, int n_in,
                              void* d_out, int out_size, void* d_ws,
                              size_t ws_size, hipStream_t stream) {
  const float* x     = (const float*)d_in[0];
  const float* table = (const float*)d_in[1];
  const float* W0    = (const float*)d_in[2];
  const float* W1    = (const float*)d_in[3];
  const float* W2    = (const float*)d_in[4];
  const float* W3    = (const float*)d_in[5];
  float* out = (float*)d_out;
  int N = in_sizes[0] / 2;

  unsigned short* Wp = (unsigned short*)d_ws;   // 147456 bf16 = 288 KB

  // Level params, double precision to match the Python reference exactly.
  LevelParams P;
  const double c = 1.2599210739135742;
  double m = 1.0;
  for (int l = 0; l < N_LEVELS; ++l) {
    double scale_d = 16.0 * m - 1.0;
    int res = (int)std::ceil(scale_d) + 1;
    long long sz = ((long long)res * res + 7) / 8 * 8;
    if (sz > (1LL << 19)) sz = 1LL << 19;
    P.scale[l] = (float)scale_d;
    P.res[l]   = res;
    P.size[l]  = (int)sz;
    m *= c;
  }

  hipLaunchKernelGGL(pack_weights_kernel, dim3(576), dim3(256), 0, stream,
                     W0, W1, W2, Wp);
  hipLaunchKernelGGL(neural_field_kernel, dim3(N / TILE_M), dim3(512), 0,
                     stream, x, table, Wp, W3, out, P);
}